// Round 4
// baseline (383.047 us; speedup 1.0000x reference)
//
#include <hip/hip_runtime.h>
#include <hip/hip_fp16.h>
#include <math.h>

#define LEAKY(x) ((x) > 0.f ? (x) : 0.01f * (x))
#define BK_SHIFT 9            // 512 nodes per bucket
#define NBMAX 128             // supports N <= 65536
#define BCAP 16384            // edges capacity per bucket (mean 8192 + ~90 sigma)
#define EPAD 64               // zeroed tail of edge_src: enables unconditional prefetch

typedef _Float16 half8 __attribute__((ext_vector_type(8)));
typedef float f32x4 __attribute__((ext_vector_type(4)));

// fp16 -> fp32 multiply-accumulate in ONE VALU op: acc += f16(lo/hi of u) * m.
// Predication folds into m (0.0 or 1.0) -> no divergent edge loop.
#define FMIX_LO(acc, u, m) \
    asm("v_fma_mix_f32 %0, %1, %2, %0 op_sel:[0,0,0] op_sel_hi:[1,0,0]" \
        : "+v"(acc) : "v"(u), "v"(m))
#define FMIX_HI(acc, u, m) \
    asm("v_fma_mix_f32 %0, %1, %2, %0 op_sel:[1,0,0] op_sel_hi:[1,0,0]" \
        : "+v"(acc) : "v"(u), "v"(m))

__device__ __forceinline__ void acc4(float (&acc)[4], uint2 u, float m) {
    FMIX_LO(acc[0], u.x, m); FMIX_HI(acc[1], u.x, m);
    FMIX_LO(acc[2], u.y, m); FMIX_HI(acc[3], u.y, m);
}

// Monotone float<->uint encoding for atomicMax on floats (incl. negatives).
__device__ __forceinline__ unsigned encf(float f) {
    unsigned u = __float_as_uint(f);
    return (u & 0x80000000u) ? ~u : (u | 0x80000000u);
}
__device__ __forceinline__ float decf(unsigned u) {
    if (u == 0u) return -INFINITY;  // never-updated cell (empty graph)
    unsigned b = (u & 0x80000000u) ? (u & 0x7fffffffu) : ~u;
    return __uint_as_float(b);
}

// Prep: transpose+convert W1..W4 to fp16 [n][k] (stride 96) once per launch;
// zero bfill, the edge_src pad tail, and the pooling accumulators.
__global__ __launch_bounds__(256) void prep(const float* __restrict__ W1,
                                            const float* __restrict__ W2,
                                            const float* __restrict__ W3,
                                            const float* __restrict__ W4,
                                            _Float16* __restrict__ WtG,
                                            int* __restrict__ bfill,
                                            int* __restrict__ epad,
                                            unsigned* __restrict__ gmaxU,
                                            float* __restrict__ gsum, int G) {
    int bi = blockIdx.x, tid = threadIdx.x;
    if (bi < 4) {
        const float* W = bi == 0 ? W1 : bi == 1 ? W2 : bi == 2 ? W3 : W4;
        _Float16* dst = WtG + bi * 9216;
        for (int idx = tid; idx < 9216; idx += 256) {
            int k = idx / 96, nn = idx % 96;
            dst[nn * 96 + k] = (_Float16)W[idx];
        }
    } else if (bi == 4) {
        for (int i2 = tid; i2 < NBMAX; i2 += 256) bfill[i2] = 0;
        for (int i2 = tid; i2 < EPAD; i2 += 256) epad[i2] = 0;
    } else if (bi == 5) {
        for (int i2 = tid; i2 < G * 96; i2 += 256) gmaxU[i2] = 0u;
    } else {
        for (int i2 = tid; i2 < G * 96; i2 += 256) gsum[i2] = 0.f;
    }
}

// Pass 1 of CSR fill: LDS counting-sort 2048-edge chunks by 512-node bucket,
// reserve per-bucket spans via bfill atomics, flush contiguous runs to tmp
// (fixed-capacity bucket-major: bucket b owns tmp[b*BCAP .. b*BCAP+BCAP)).
__global__ __launch_bounds__(256) void bin_kernel(const int* __restrict__ src,
                                                  const int* __restrict__ dst,
                                                  int* __restrict__ bfill,
                                                  uint2* __restrict__ tmp,
                                                  int E, int nb) {
    __shared__ int hist[NBMAX];
    __shared__ int scanbuf[NBMAX];
    __shared__ int lofs[NBMAX];
    __shared__ int adj[NBMAX];
    __shared__ uint2 buf[2048];
    __shared__ unsigned char bkt_of[2048];
    int base = blockIdx.x * 2048;
    int cnt = min(2048, E - base);
    int tid = threadIdx.x;
    for (int b = tid; b < NBMAX; b += 256) hist[b] = 0;
    __syncthreads();
    int es[8], ed[8];
#pragma unroll
    for (int k = 0; k < 8; ++k) {
        int l = tid + k * 256;
        if (l < cnt) {
            es[k] = src[base + l];
            ed[k] = dst[base + l];
            atomicAdd(&hist[ed[k] >> BK_SHIFT], 1);
        }
    }
    __syncthreads();
    if (tid < NBMAX) scanbuf[tid] = hist[tid];
    __syncthreads();
    for (int off = 1; off < NBMAX; off <<= 1) {
        int t = (tid < NBMAX && tid >= off) ? scanbuf[tid - off] : 0;
        __syncthreads();
        if (tid < NBMAX) scanbuf[tid] += t;
        __syncthreads();
    }
    if (tid < nb) {
        int cb = hist[tid];
        int start = scanbuf[tid] - cb;   // exclusive (position in buf)
        lofs[tid] = start;
        int g = (cb > 0) ? atomicAdd(&bfill[tid], cb) : 0;
        adj[tid] = tid * BCAP + g - start;  // buf idx -> tmp idx shift
    }
    __syncthreads();
#pragma unroll
    for (int k = 0; k < 8; ++k) {
        int l = tid + k * 256;
        if (l < cnt) {
            int b = ed[k] >> BK_SHIFT;
            int r = atomicAdd(&lofs[b], 1);
            buf[r] = make_uint2((unsigned)es[k], (unsigned)ed[k]);
            bkt_of[r] = (unsigned char)b;
        }
    }
    __syncthreads();
    for (int j = tid; j < cnt; j += 256) {
        int b = bkt_of[j];
        tmp[adj[b] + j] = buf[j];
    }
}

// Pass 2: one block per 512-node bucket. Per-node in-degree (LDS hist), local
// scan -> row_ptr, dis = rsqrt(deg+1), layer-0 pre-scale Z0 = dis*x, and the
// final edge scatter with LDS cursors. Everything stays inside one CU.
__global__ __launch_bounds__(512) void place2(const uint2* __restrict__ tmp,
                                              const int* __restrict__ bfill,
                                              const float* __restrict__ X,
                                              float* __restrict__ dis,
                                              int* __restrict__ row_ptr,
                                              int* __restrict__ edge_src,
                                              float* __restrict__ Z0, int kq,
                                              int n, int E, int nb) {
    __shared__ int hist[512];
    __shared__ int sc[512];
    __shared__ int sbf[NBMAX];
    __shared__ int bb_s;
    int b = blockIdx.x;
    int tid = threadIdx.x;
    if (tid < NBMAX) sbf[tid] = (tid < nb) ? bfill[tid] : 0;
    hist[tid] = 0;
    __syncthreads();
    if (tid == 0) {
        int s = 0;
        for (int k = 0; k < b; ++k) s += sbf[k];
        bb_s = s;
    }
    __syncthreads();
    int bb = bb_s;
    int cnt = sbf[b];
    const uint2* mybkt = tmp + (size_t)b * BCAP;
    int node0 = b << BK_SHIFT;
    for (int j = tid; j < cnt; j += 512)
        atomicAdd(&hist[(int)mybkt[j].y - node0], 1);
    __syncthreads();
    int v = hist[tid];
    sc[tid] = v;
    __syncthreads();
    for (int off = 1; off < 512; off <<= 1) {
        int t = (tid >= off) ? sc[tid - off] : 0;
        __syncthreads();
        sc[tid] += t;
        __syncthreads();
    }
    int excl = sc[tid] - v;
    int i = node0 + tid;
    if (i < n) {
        row_ptr[i] = bb + excl;
        float di = rsqrtf((float)(v + 1));  // +1: self-loop
        dis[i] = di;
        const float4* X4 = (const float4*)X;
        float4* Z4 = (float4*)Z0;
        for (int j = 0; j < kq; ++j) {
            float4 xv = X4[(size_t)i * kq + j];
            Z4[(size_t)i * kq + j] = make_float4(di * xv.x, di * xv.y, di * xv.z, di * xv.w);
        }
    }
    if (b == 0 && tid == 0) row_ptr[n] = E;
    __syncthreads();
    hist[tid] = bb + excl;  // reuse as LDS cursor
    __syncthreads();
    for (int j = tid; j < cnt; j += 512) {
        uint2 ev = mybkt[j];
        int pos = atomicAdd(&hist[(int)ev.y - node0], 1);
        edge_src[pos] = (int)ev.x;
    }
}

// fp32 wave-per-node aggregation (layer 0, 16-wide rows). 16 edge-groups x
// 4 float4-lanes. 2-deep unconditional prefetch; dummy edge indices CLAMPED
// to re0 so they hit an already-cached row (no random traffic amplification).
__global__ __launch_bounds__(256) void agg_wave0(const float* __restrict__ Z,
                                                 const float* __restrict__ dis,
                                                 const int* __restrict__ row_ptr,
                                                 const int* __restrict__ edge_src,
                                                 float* __restrict__ A, int n) {
    int i = (blockIdx.x * 256 + threadIdx.x) >> 6;  // node = global wave id
    if (i >= n) return;
    int lane = threadIdx.x & 63;
    int g = lane >> 2;   // edge group 0-15
    int c = lane & 3;    // float4 lane
    const float4* Z4 = (const float4*)Z;
    float di = dis[i];
    size_t base = (size_t)i * 4 + c;
    float4 acc = (g == 0) ? Z4[base] : make_float4(0.f, 0.f, 0.f, 0.f);
    int re0 = row_ptr[i], re1 = row_ptr[i + 1];
    int e0 = re0 + g;
    int ec0 = (e0 < re1) ? e0 : re0;
    int ec1 = (e0 + 16 < re1) ? e0 + 16 : re0;
    int s0 = edge_src[ec0];
    int s1 = edge_src[ec1];
    float m0 = (e0 < re1) ? 1.f : 0.f;
    float m1 = (e0 + 16 < re1) ? 1.f : 0.f;
    float4 u0 = Z4[(size_t)s0 * 4 + c];
    float4 u1 = Z4[(size_t)s1 * 4 + c];
    acc.x = fmaf(u0.x, m0, acc.x); acc.y = fmaf(u0.y, m0, acc.y);
    acc.z = fmaf(u0.z, m0, acc.z); acc.w = fmaf(u0.w, m0, acc.w);
    acc.x = fmaf(u1.x, m1, acc.x); acc.y = fmaf(u1.y, m1, acc.y);
    acc.z = fmaf(u1.z, m1, acc.z); acc.w = fmaf(u1.w, m1, acc.w);
    for (int e = e0 + 32; e < re1; e += 16) {  // rare heavy nodes
        int s = edge_src[e];
        float4 u = Z4[(size_t)s * 4 + c];
        acc.x += u.x; acc.y += u.y; acc.z += u.z; acc.w += u.w;
    }
#pragma unroll
    for (int m = 4; m < 64; m <<= 1) {
        acc.x += __shfl_xor(acc.x, m);
        acc.y += __shfl_xor(acc.y, m);
        acc.z += __shfl_xor(acc.z, m);
        acc.w += __shfl_xor(acc.w, m);
    }
    if (g == 0)
        ((float4*)A)[base] = make_float4(di * acc.x, di * acc.y,
                                         di * acc.z, di * acc.w);
}

// fp16 wave-per-node aggregation over ONE 32-feature plane (layers 1-4).
// Z and A are stored as 3 planes of [n][32] halves (3.2 MB each < 4 MB
// per-XCD L2). grid = 3*nbw: plane = blockIdx/nbw -> block dispatch order
// gives coarse temporal phase separation, so the L2 working set per phase
// is one plane instead of 9.6 MB (the round-3 counters showed the random
// gather was bound by the L2-miss path at ~2 TB/s). Per lane per edge:
// one 8 B load + 4 v_fma_mix. 8 edge-groups x 8 feature-lanes; 4-deep
// unconditional prefetch with dummy indices clamped to re0 (cached row).
__global__ __launch_bounds__(256) void agg_wave_hp(const __half* __restrict__ Zh,
                                                   const float* __restrict__ dis,
                                                   const int* __restrict__ row_ptr,
                                                   const int* __restrict__ edge_src,
                                                   __half* __restrict__ A,
                                                   int n, int nbw) {
    int bi = blockIdx.x;
    int plane = bi / nbw;
    int wi = bi - plane * nbw;
    int i = (wi * 256 + threadIdx.x) >> 6;  // node = plane-local wave id
    if (i >= n) return;
    int lane = threadIdx.x & 63;
    int g = lane >> 3;    // edge group 0-7
    int c = lane & 7;     // uint2 lane: halves [4c, 4c+4) of the plane
    const uint2* Zp = (const uint2*)Zh + (size_t)plane * n * 8;
    uint2* Ap = (uint2*)A + (size_t)plane * n * 8;
    float di = dis[i];
    float acc[4];
#pragma unroll
    for (int k = 0; k < 4; ++k) acc[k] = 0.f;
    int re0 = row_ptr[i], re1 = row_ptr[i + 1];
    int e0 = re0 + g;
    int s[4]; float m[4];
#pragma unroll
    for (int k = 0; k < 4; ++k) {
        int e = e0 + k * 8;
        int ec = (e < re1) ? e : re0;  // clamp: dummy hits a cached row
        s[k] = edge_src[ec];
        m[k] = (e < re1) ? 1.0f : 0.0f;
    }
    uint2 u[4];
#pragma unroll
    for (int k = 0; k < 4; ++k) u[k] = Zp[(size_t)s[k] * 8 + c];
    if (g == 0) acc4(acc, Zp[(size_t)i * 8 + c], 1.0f);  // self-loop
#pragma unroll
    for (int k = 0; k < 4; ++k) acc4(acc, u[k], m[k]);
    for (int e = e0 + 32; e < re1; e += 8) {  // rare heavy nodes
        int s2 = edge_src[e];
        acc4(acc, Zp[(size_t)s2 * 8 + c], 1.0f);
    }
    // Butterfly reduce across the 8 edge groups.
#pragma unroll
    for (int m2 = 8; m2 < 64; m2 <<= 1) {
#pragma unroll
        for (int k = 0; k < 4; ++k) acc[k] += __shfl_xor(acc[k], m2);
    }
    if (g == 0) {
        __half2 h0 = __floats2half2_rn(di * acc[0], di * acc[1]);
        __half2 h1 = __floats2half2_rn(di * acc[2], di * acc[3]);
        uint2 o;
        o.x = *(unsigned*)&h0; o.y = *(unsigned*)&h1;
        Ap[(size_t)i * 8 + c] = o;
    }
}

// LDS-free MFMA GEMM (96x96, fp16 operands, fp32 accum). A and Xn are in
// 3-plane layout ([plane][n][32] halves) -> plane kc IS the kc-th A-fragment.
// Wt is pre-transposed fp16 [f][k] stride 96 (18 KB, L2-resident).
// Fragment layouts (HW-verified, docs §3): A[m=lane&15][k=q*8+j],
// B[k=q*8+j][n=lane&15], D col=lane&15 row=q*4+reg.
template <bool SCALE>
__global__ __launch_bounds__(256) void gemm_mfma(const __half* __restrict__ A,
                                                 const _Float16* __restrict__ Wt,
                                                 const float* __restrict__ b,
                                                 const float* __restrict__ dis,
                                                 __half* __restrict__ Xn, int n) {
    int tid = threadIdx.x;
    int i0 = blockIdx.x * 64;
    int w = tid >> 6, lane = tid & 63;
    int q = lane >> 4, c = lane & 15;
    int arow = i0 + w * 16 + c;
    const _Float16* Ap = (const _Float16*)A;
    size_t pstride = (size_t)n * 32;  // halves per plane
    half8 af[3];
    if (arow < n) {
#pragma unroll
        for (int kc = 0; kc < 3; ++kc)
            af[kc] = *(const half8*)&Ap[kc * pstride + (size_t)arow * 32 + q * 8];
    } else {
#pragma unroll
        for (int kc = 0; kc < 3; ++kc)
#pragma unroll
            for (int j = 0; j < 8; ++j) af[kc][j] = (_Float16)0.f;
    }
    float dvals[4];
#pragma unroll
    for (int r = 0; r < 4; ++r) {
        int gi = i0 + w * 16 + q * 4 + r;
        dvals[r] = (SCALE && gi < n) ? dis[gi] : 1.f;
    }
#pragma unroll
    for (int nt = 0; nt < 6; ++nt) {
        f32x4 acc = {0.f, 0.f, 0.f, 0.f};
#pragma unroll
        for (int kc = 0; kc < 3; ++kc) {
            half8 bf = *(const half8*)&Wt[(size_t)(nt * 16 + c) * 96 + kc * 32 + q * 8];
            acc = __builtin_amdgcn_mfma_f32_16x16x32_f16(af[kc], bf, acc, 0, 0, 0);
        }
        int col = nt * 16 + c;
        float bias = b[col];
#pragma unroll
        for (int r = 0; r < 4; ++r) {
            int gi = i0 + w * 16 + q * 4 + r;
            if (gi < n) {
                float v = acc[r] + bias;
                v = LEAKY(v);
                if (SCALE) v *= dvals[r];
                ((_Float16*)Xn)[(size_t)(col >> 5) * pstride +
                                (size_t)gi * 32 + (col & 31)] = (_Float16)v;
            }
        }
    }
}

// Last-layer GEMM with fused max/mean pooling: never materializes H.
// A in 3-plane layout (see gemm_mfma).
__global__ __launch_bounds__(256) void gemm_pool(const __half* __restrict__ A,
                                                 const _Float16* __restrict__ Wt,
                                                 const float* __restrict__ b,
                                                 const int* __restrict__ batch,
                                                 unsigned* __restrict__ gmaxU,
                                                 float* __restrict__ gsum, int n) {
    __shared__ float pmaxs[4][96];
    __shared__ float psums[4][96];
    int tid = threadIdx.x;
    int i0 = blockIdx.x * 64;
    int w = tid >> 6, lane = tid & 63;
    int q = lane >> 4, c = lane & 15;
    int arow = i0 + w * 16 + c;
    const _Float16* Ap = (const _Float16*)A;
    size_t pstride = (size_t)n * 32;
    half8 af[3];
    if (arow < n) {
#pragma unroll
        for (int kc = 0; kc < 3; ++kc)
            af[kc] = *(const half8*)&Ap[kc * pstride + (size_t)arow * 32 + q * 8];
    } else {
#pragma unroll
        for (int kc = 0; kc < 3; ++kc)
#pragma unroll
            for (int j = 0; j < 8; ++j) af[kc][j] = (_Float16)0.f;
    }
    int row0 = i0 + w * 16;
    bool wuni = (row0 + 15 < n) && (batch[row0] == batch[row0 + 15]);
    bool buni = (i0 + 63 < n) && (batch[i0] == batch[i0 + 63]);
    int gw = wuni ? batch[row0] : 0;
#pragma unroll
    for (int nt = 0; nt < 6; ++nt) {
        f32x4 acc = {0.f, 0.f, 0.f, 0.f};
#pragma unroll
        for (int kc = 0; kc < 3; ++kc) {
            half8 bf = *(const half8*)&Wt[(size_t)(nt * 16 + c) * 96 + kc * 32 + q * 8];
            acc = __builtin_amdgcn_mfma_f32_16x16x32_f16(af[kc], bf, acc, 0, 0, 0);
        }
        int col = nt * 16 + c;
        float bias = b[col];
        float v[4];
#pragma unroll
        for (int r = 0; r < 4; ++r) {
            float t = acc[r] + bias;
            v[r] = LEAKY(t);
        }
        if (wuni) {
            float mx = fmaxf(fmaxf(v[0], v[1]), fmaxf(v[2], v[3]));
            float sm = v[0] + v[1] + v[2] + v[3];
            mx = fmaxf(mx, __shfl_xor(mx, 16)); sm += __shfl_xor(sm, 16);
            mx = fmaxf(mx, __shfl_xor(mx, 32)); sm += __shfl_xor(sm, 32);
            if (buni) {
                if (q == 0) { pmaxs[w][col] = mx; psums[w][col] = sm; }
            } else if (q == 0) {
                atomicMax(&gmaxU[gw * 96 + col], encf(mx));
                atomicAdd(&gsum[gw * 96 + col], sm);
            }
        } else {
            int r = 0;
            while (r < 4) {
                int gi = i0 + w * 16 + q * 4 + r;
                if (gi >= n) break;
                int gb = batch[gi];
                float mx = v[r], sm = v[r];
                int r2 = r + 1;
                for (; r2 < 4; ++r2) {
                    int gi2 = i0 + w * 16 + q * 4 + r2;
                    if (gi2 >= n || batch[gi2] != gb) break;
                    mx = fmaxf(mx, v[r2]); sm += v[r2];
                }
                atomicMax(&gmaxU[gb * 96 + col], encf(mx));
                atomicAdd(&gsum[gb * 96 + col], sm);
                r = r2;
            }
        }
    }
    __syncthreads();
    if (buni && tid < 96) {
        float m = fmaxf(fmaxf(pmaxs[0][tid], pmaxs[1][tid]),
                        fmaxf(pmaxs[2][tid], pmaxs[3][tid]));
        float s = psums[0][tid] + psums[1][tid] + psums[2][tid] + psums[3][tid];
        int gb = batch[i0];
        atomicMax(&gmaxU[gb * 96 + tid], encf(m));
        atomicAdd(&gsum[gb * 96 + tid], s);
    }
}

// VALU GEMM for layer 0 (K=16): Xn = leaky(A@W + b) * dis, fp16 out in
// 3-plane layout ([plane][n][32] halves).
__global__ __launch_bounds__(192) void gemm_l0(const float* __restrict__ A,
                                               const float* __restrict__ W,
                                               const float* __restrict__ b,
                                               const float* __restrict__ dis,
                                               __half* __restrict__ Xn, int n) {
    constexpr int KQ = 4;
    __shared__ __align__(16) float4 Al[64 * KQ];
    int tid = threadIdx.x;
    int i0 = blockIdx.x * 64;
    for (int idx = tid; idx < 64 * KQ; idx += 192) {
        int gi = i0 + idx / KQ;
        Al[idx] = (gi < n) ? ((const float4*)A)[(size_t)i0 * KQ + idx]
                           : make_float4(0.f, 0.f, 0.f, 0.f);
    }
    __syncthreads();
    int fq = tid % 24;
    int g = tid / 24;
    const float4* W4 = (const float4*)W;
    float4 bb = ((const float4*)b)[fq];
    float4 acc[8];
#pragma unroll
    for (int r = 0; r < 8; ++r) acc[r] = bb;
    for (int kc = 0; kc < 16; kc += 8) {
        float4 w[8];
#pragma unroll
        for (int kk = 0; kk < 8; ++kk) w[kk] = W4[(size_t)(kc + kk) * 24 + fq];
#pragma unroll
        for (int r = 0; r < 8; ++r) {
            const float4* ar = &Al[(g * 8 + r) * KQ + (kc >> 2)];
#pragma unroll
            for (int k4 = 0; k4 < 2; ++k4) {
                float4 a = ar[k4];
                float4 w0 = w[4 * k4 + 0], w1 = w[4 * k4 + 1];
                float4 w2 = w[4 * k4 + 2], w3 = w[4 * k4 + 3];
                acc[r].x += a.x * w0.x + a.y * w1.x + a.z * w2.x + a.w * w3.x;
                acc[r].y += a.x * w0.y + a.y * w1.y + a.z * w2.y + a.w * w3.y;
                acc[r].z += a.x * w0.z + a.y * w1.z + a.z * w2.z + a.w * w3.z;
                acc[r].w += a.x * w0.w + a.y * w1.w + a.z * w2.w + a.w * w3.w;
            }
        }
    }
#pragma unroll
    for (int r = 0; r < 8; ++r) {
        int gi = i0 + g * 8 + r;
        if (gi < n) {
            float di = dis[gi];
            float4 o;
            o.x = di * LEAKY(acc[r].x); o.y = di * LEAKY(acc[r].y);
            o.z = di * LEAKY(acc[r].z); o.w = di * LEAKY(acc[r].w);
            __half2 h0 = __floats2half2_rn(o.x, o.y);
            __half2 h1 = __floats2half2_rn(o.z, o.w);
            uint2 u;
            u.x = *(unsigned*)&h0;
            u.y = *(unsigned*)&h1;
            // plane = fq>>3, within-plane uint2 index = fq&7
            ((uint2*)Xn)[(size_t)(fq >> 3) * n * 8 + (size_t)gi * 8 + (fq & 7)] = u;
        }
    }
}

__device__ __forceinline__ int lower_bound(const int* b, int n, int v) {
    int lo = 0, hi = n;
    while (lo < hi) {
        int m = (lo + hi) >> 1;
        if (b[m] < v) lo = m + 1; else hi = m;
    }
    return lo;
}

// Pool decode + MLP head: grid = G, block = 96.
__global__ void pool_final(const unsigned* __restrict__ gmaxU,
                           const float* __restrict__ gsum,
                           const int* __restrict__ batch,
                           const float* __restrict__ Wo1, const float* __restrict__ bo1,
                           const float* __restrict__ Wo2, const float* __restrict__ bo2,
                           float* __restrict__ out, int n) {
    __shared__ float pooled[192];
    __shared__ float sh[96];
    int g = blockIdx.x, f = threadIdx.x;
    int s = lower_bound(batch, n, g), e = lower_bound(batch, n, g + 1);
    float cnt = fmaxf((float)(e - s), 1.f);
    pooled[f] = decf(gmaxU[(size_t)g * 96 + f]);
    pooled[96 + f] = gsum[(size_t)g * 96 + f] / cnt;
    __syncthreads();
    float acc = bo1[f];
    for (int k = 0; k < 192; ++k) acc += pooled[k] * Wo1[k * 96 + f];
    float a = LEAKY(acc);
    sh[f] = a * Wo2[f];
    __syncthreads();
    if (f == 0) {
        float sacc = 0.f;
        for (int k = 0; k < 96; ++k) sacc += sh[k];
        out[g] = sacc + bo2[0];
    }
}

extern "C" void kernel_launch(void* const* d_in, const int* in_sizes, int n_in,
                              void* d_out, int out_size, void* d_ws, size_t ws_size,
                              hipStream_t stream) {
    const float* x      = (const float*)d_in[0];
    const int*   eidx   = (const int*)d_in[1];
    const int*   batch  = (const int*)d_in[2];
    const float* W_init = (const float*)d_in[3];
    const float* b_init = (const float*)d_in[4];
    const float* W1 = (const float*)d_in[5];  const float* b1 = (const float*)d_in[6];
    const float* W2 = (const float*)d_in[7];  const float* b2 = (const float*)d_in[8];
    const float* W3 = (const float*)d_in[9];  const float* b3 = (const float*)d_in[10];
    const float* W4 = (const float*)d_in[11]; const float* b4 = (const float*)d_in[12];
    const float* Wo1 = (const float*)d_in[13]; const float* bo1 = (const float*)d_in[14];
    const float* Wo2 = (const float*)d_in[15]; const float* bo2 = (const float*)d_in[16];
    float* out = (float*)d_out;

    const int N = in_sizes[2];
    const int E = in_sizes[1] / 2;
    const int G = out_size;
    const int* src = eidx;
    const int* dst = eidx + E;

    const int nbBkt  = (N + (1 << BK_SHIFT) - 1) >> BK_SHIFT;

    char* ws = (char*)d_ws;
    size_t off = 0;
    auto alloc = [&](size_t bytes) {
        size_t o = off;
        off += (bytes + 255) & ~(size_t)255;
        return o;
    };
    float*    dis      = (float*)(ws + alloc((size_t)N * 4));
    int*      row_ptr  = (int*)(ws + alloc((size_t)(N + 1) * 4));
    int*      bfill    = (int*)(ws + alloc(NBMAX * 4));
    unsigned* gmaxU    = (unsigned*)(ws + alloc((size_t)G * 96 * 4));
    float*    gsumB    = (float*)(ws + alloc((size_t)G * 96 * 4));
    int*      edge_src = (int*)(ws + alloc((size_t)(E + EPAD) * 4));
    float*    Z0       = (float*)(ws + alloc((size_t)N * 16 * 4));
    __half*   ZA       = (__half*)(ws + alloc((size_t)N * 96 * 2));
    __half*   ZB       = (__half*)(ws + alloc((size_t)N * 96 * 2));
    __half*   AggH     = (__half*)(ws + alloc((size_t)N * 96 * 2));
    float*    Agg0     = (float*)(ws + alloc((size_t)N * 16 * 4));
    _Float16* WtG      = (_Float16*)(ws + alloc((size_t)4 * 9216 * 2));
    uint2*    tmp      = (uint2*)(ws + alloc((size_t)nbBkt * BCAP * 8));
    (void)ws_size; (void)n_in;

    const int nbWave = (N + 3) / 4;       // 4 nodes (waves) per 256-thread block
    const int nbTile = (N + 63) / 64;

    prep<<<7, 256, 0, stream>>>(W1, W2, W3, W4, WtG, bfill, edge_src + E,
                                gmaxU, gsumB, G);
    bin_kernel<<<(E + 2047) / 2048, 256, 0, stream>>>(src, dst, bfill, tmp, E, nbBkt);
    place2<<<nbBkt, 512, 0, stream>>>(tmp, bfill, x, dis, row_ptr, edge_src, Z0,
                                      4, N, E, nbBkt);

    // Layer 0: fp32 agg of pre-scaled 16-wide input, then 16x96 VALU GEMM
    // -> fp16 Z1 in 3-plane layout.
    agg_wave0<<<nbWave, 256, 0, stream>>>(Z0, dis, row_ptr, edge_src, Agg0, N);
    gemm_l0<<<nbTile, 192, 0, stream>>>(Agg0, W_init, b_init, dis, ZA, N);

    const float* bs[4] = {b1, b2, b3, b4};
    __half* cur = ZA;
    __half* nxt = ZB;
    for (int l = 0; l < 4; ++l) {
        agg_wave_hp<<<3 * nbWave, 256, 0, stream>>>(cur, dis, row_ptr, edge_src,
                                                    AggH, N, nbWave);
        if (l < 3) {
            gemm_mfma<true><<<nbTile, 256, 0, stream>>>(AggH, WtG + l * 9216, bs[l],
                                                        dis, nxt, N);
            __half* t = cur; cur = nxt; nxt = t;
        } else {  // last layer: fused pooling, H never materialized
            gemm_pool<<<nbTile, 256, 0, stream>>>(AggH, WtG + 3 * 9216, bs[3],
                                                  batch, gmaxU, gsumB, N);
        }
    }

    pool_final<<<G, 96, 0, stream>>>(gmaxU, gsumB, batch, Wo1, bo1, Wo2, bo2, out, N);
}

// Round 5
// 377.586 us; speedup vs baseline: 1.0145x; 1.0145x over previous
//
#include <hip/hip_runtime.h>
#include <hip/hip_fp16.h>
#include <math.h>

#define LEAKY(x) ((x) > 0.f ? (x) : 0.01f * (x))
#define EPAD 64               // zeroed tail of edge_src: enables unconditional prefetch
#define SCANB 1024            // nodes per scan_a block

typedef _Float16 half8 __attribute__((ext_vector_type(8)));
typedef float f32x4 __attribute__((ext_vector_type(4)));

// fp16 -> fp32 multiply-accumulate in ONE VALU op: acc += f16(lo/hi of u) * m.
// Predication folds into m (0.0 or 1.0) -> no divergent edge loop.
#define FMIX_LO(acc, u, m) \
    asm("v_fma_mix_f32 %0, %1, %2, %0 op_sel:[0,0,0] op_sel_hi:[1,0,0]" \
        : "+v"(acc) : "v"(u), "v"(m))
#define FMIX_HI(acc, u, m) \
    asm("v_fma_mix_f32 %0, %1, %2, %0 op_sel:[1,0,0] op_sel_hi:[1,0,0]" \
        : "+v"(acc) : "v"(u), "v"(m))

__device__ __forceinline__ void acc12(float (&acc)[12], uint2 u0, uint2 u1,
                                      uint2 u2, float m) {
    FMIX_LO(acc[0], u0.x, m);  FMIX_HI(acc[1], u0.x, m);
    FMIX_LO(acc[2], u0.y, m);  FMIX_HI(acc[3], u0.y, m);
    FMIX_LO(acc[4], u1.x, m);  FMIX_HI(acc[5], u1.x, m);
    FMIX_LO(acc[6], u1.y, m);  FMIX_HI(acc[7], u1.y, m);
    FMIX_LO(acc[8], u2.x, m);  FMIX_HI(acc[9], u2.x, m);
    FMIX_LO(acc[10], u2.y, m); FMIX_HI(acc[11], u2.y, m);
}

// Monotone float<->uint encoding for atomicMax on floats (incl. negatives).
__device__ __forceinline__ unsigned encf(float f) {
    unsigned u = __float_as_uint(f);
    return (u & 0x80000000u) ? ~u : (u | 0x80000000u);
}
__device__ __forceinline__ float decf(unsigned u) {
    if (u == 0u) return -INFINITY;  // never-updated cell (empty graph)
    unsigned b = (u & 0x80000000u) ? (u & 0x7fffffffu) : ~u;
    return __uint_as_float(b);
}

// Prep: transpose+convert W1..W4 to fp16 [n][k] (stride 96) once per launch;
// zero deg, the edge_src pad tail, and the pooling accumulators.
__global__ __launch_bounds__(256) void prep(const float* __restrict__ W1,
                                            const float* __restrict__ W2,
                                            const float* __restrict__ W3,
                                            const float* __restrict__ W4,
                                            _Float16* __restrict__ WtG,
                                            int* __restrict__ deg,
                                            int* __restrict__ epad,
                                            unsigned* __restrict__ gmaxU,
                                            float* __restrict__ gsum,
                                            int n, int G) {
    int bi = blockIdx.x, tid = threadIdx.x;
    if (bi < 4) {
        const float* W = bi == 0 ? W1 : bi == 1 ? W2 : bi == 2 ? W3 : W4;
        _Float16* dst = WtG + bi * 9216;
        for (int idx = tid; idx < 9216; idx += 256) {
            int k = idx / 96, nn = idx % 96;
            dst[nn * 96 + k] = (_Float16)W[idx];
        }
    } else {
        int t = (bi - 4) * 256 + tid;
        int stride = (gridDim.x - 4) * 256;
        for (int i2 = t; i2 < n; i2 += stride) deg[i2] = 0;
        for (int i2 = t; i2 < G * 96; i2 += stride) { gmaxU[i2] = 0u; gsum[i2] = 0.f; }
        for (int i2 = t; i2 < EPAD; i2 += stride) epad[i2] = 0;
    }
}

// CSR build, fully parallel (replaces the old 98-block bucket pipeline):
// 1) global-atomic in-degree histogram over dst (200 KB counters, L2-resident)
__global__ __launch_bounds__(256) void hist_kernel(const int* __restrict__ dst,
                                                   int* __restrict__ deg, int E) {
    int e = blockIdx.x * 256 + threadIdx.x;
    if (e < E) atomicAdd(&deg[dst[e]], 1);
}

// 2a) block-local exclusive scan of deg (1024 nodes/block, 4/thread)
__global__ __launch_bounds__(256) void scan_a(const int* __restrict__ deg,
                                              int* __restrict__ rp,
                                              int* __restrict__ bsum, int n) {
    __shared__ int sc[256];
    int tid = threadIdx.x;
    int base = blockIdx.x * SCANB + tid * 4;
    int4 d = make_int4(0, 0, 0, 0);
    if (base + 3 < n) d = *(const int4*)&deg[base];
    else {
        if (base < n) d.x = deg[base];
        if (base + 1 < n) d.y = deg[base + 1];
        if (base + 2 < n) d.z = deg[base + 2];
    }
    int s = d.x + d.y + d.z + d.w;
    sc[tid] = s;
    __syncthreads();
    for (int off = 1; off < 256; off <<= 1) {
        int t = (tid >= off) ? sc[tid - off] : 0;
        __syncthreads();
        sc[tid] += t;
        __syncthreads();
    }
    int excl = sc[tid] - s;
    int r0 = excl, r1 = r0 + d.x, r2 = r1 + d.y, r3 = r2 + d.z;
    if (base + 3 < n) *(int4*)&rp[base] = make_int4(r0, r1, r2, r3);
    else {
        if (base < n) rp[base] = r0;
        if (base + 1 < n) rp[base + 1] = r1;
        if (base + 2 < n) rp[base + 2] = r2;
    }
    if (tid == 255) bsum[blockIdx.x] = sc[255];
}

// 2b) scan of the block sums (single block; supports up to 64 scan_a blocks
// i.e. N <= 65536). Overwrites bsum with its exclusive scan.
__global__ __launch_bounds__(64) void scan_b(int* __restrict__ bsum, int nb) {
    __shared__ int sc[64];
    int tid = threadIdx.x;
    int v = (tid < nb) ? bsum[tid] : 0;
    sc[tid] = v;
    __syncthreads();
    for (int off = 1; off < 64; off <<= 1) {
        int t = (tid >= off) ? sc[tid - off] : 0;
        __syncthreads();
        sc[tid] += t;
        __syncthreads();
    }
    bsum[tid] = sc[tid] - v;
}

// 2c) finalize: rp += block offset; cur = rp (scatter cursors);
// dis = rsqrt(deg+1); Z0 = dis * x (layer-0 pre-scale). Thread per node.
__global__ __launch_bounds__(256) void scan_c(int* __restrict__ rp,
                                              int* __restrict__ cur,
                                              const int* __restrict__ bsum,
                                              const int* __restrict__ deg,
                                              const float* __restrict__ X,
                                              float* __restrict__ dis,
                                              float* __restrict__ Z0,
                                              int n, int E) {
    int i = blockIdx.x * 256 + threadIdx.x;
    if (i == 0) rp[n] = E;
    if (i >= n) return;
    int r = rp[i] + bsum[i >> 10];
    rp[i] = r;
    cur[i] = r;
    float di = rsqrtf((float)(deg[i] + 1));  // +1: self-loop
    dis[i] = di;
    const float4* X4 = (const float4*)X;
    float4* Z4 = (float4*)Z0;
#pragma unroll
    for (int j = 0; j < 4; ++j) {
        float4 xv = X4[(size_t)i * 4 + j];
        Z4[(size_t)i * 4 + j] = make_float4(di * xv.x, di * xv.y,
                                            di * xv.z, di * xv.w);
    }
}

// 3) edge scatter via per-node atomic cursors. Edge order within a node's
// list is nondeterministic (fp32 sum reorder ~1e-6 - tolerated).
__global__ __launch_bounds__(256) void scatter_kernel(const int* __restrict__ src,
                                                      const int* __restrict__ dst,
                                                      int* __restrict__ cur,
                                                      int* __restrict__ edge_src,
                                                      int E) {
    int e = blockIdx.x * 256 + threadIdx.x;
    if (e < E) {
        int s = src[e], d = dst[e];
        int pos = atomicAdd(&cur[d], 1);
        edge_src[pos] = s;
    }
}

// fp32 wave-per-node aggregation (layer 0, 16-wide rows). 16 edge-groups x
// 4 float4-lanes. 2-deep unconditional prefetch; dummy edge indices CLAMPED
// to re0 so they hit an already-cached row.
__global__ __launch_bounds__(256) void agg_wave0(const float* __restrict__ Z,
                                                 const float* __restrict__ dis,
                                                 const int* __restrict__ row_ptr,
                                                 const int* __restrict__ edge_src,
                                                 float* __restrict__ A, int n) {
    int i = (blockIdx.x * 256 + threadIdx.x) >> 6;  // node = global wave id
    if (i >= n) return;
    int lane = threadIdx.x & 63;
    int g = lane >> 2;   // edge group 0-15
    int c = lane & 3;    // float4 lane
    const float4* Z4 = (const float4*)Z;
    float di = dis[i];
    size_t base = (size_t)i * 4 + c;
    float4 acc = (g == 0) ? Z4[base] : make_float4(0.f, 0.f, 0.f, 0.f);
    int re0 = row_ptr[i], re1 = row_ptr[i + 1];
    int e0 = re0 + g;
    int ec0 = (e0 < re1) ? e0 : re0;
    int ec1 = (e0 + 16 < re1) ? e0 + 16 : re0;
    int s0 = edge_src[ec0];
    int s1 = edge_src[ec1];
    float m0 = (e0 < re1) ? 1.f : 0.f;
    float m1 = (e0 + 16 < re1) ? 1.f : 0.f;
    float4 u0 = Z4[(size_t)s0 * 4 + c];
    float4 u1 = Z4[(size_t)s1 * 4 + c];
    acc.x = fmaf(u0.x, m0, acc.x); acc.y = fmaf(u0.y, m0, acc.y);
    acc.z = fmaf(u0.z, m0, acc.z); acc.w = fmaf(u0.w, m0, acc.w);
    acc.x = fmaf(u1.x, m1, acc.x); acc.y = fmaf(u1.y, m1, acc.y);
    acc.z = fmaf(u1.z, m1, acc.z); acc.w = fmaf(u1.w, m1, acc.w);
    for (int e = e0 + 32; e < re1; e += 16) {  // rare heavy nodes
        int s = edge_src[e];
        float4 u = Z4[(size_t)s * 4 + c];
        acc.x += u.x; acc.y += u.y; acc.z += u.z; acc.w += u.w;
    }
#pragma unroll
    for (int m = 4; m < 64; m <<= 1) {
        acc.x += __shfl_xor(acc.x, m);
        acc.y += __shfl_xor(acc.y, m);
        acc.z += __shfl_xor(acc.z, m);
        acc.w += __shfl_xor(acc.w, m);
    }
    if (g == 0)
        ((float4*)A)[base] = make_float4(di * acc.x, di * acc.y,
                                         di * acc.z, di * acc.w);
}

// fp16 wave-per-node aggregation, 96-wide (layers 1-4). 8 edge-groups x
// 8 feature-lanes (24 B/lane). 4-deep unconditional batched prefetch:
// 4 edge indices + 12 row loads independent & in flight; deg<=32 branch-free;
// dummy indices clamped to re0 (cached row). Overflow loop for the ~1e-4
// tail. This structure measured ~35 us/layer vs 77 MB compulsory L2-fill
// floor (round-4 analysis) - near its structural service-rate limit.
__global__ __launch_bounds__(256) void agg_wave_h(const __half* __restrict__ Zh,
                                                  const float* __restrict__ dis,
                                                  const int* __restrict__ row_ptr,
                                                  const int* __restrict__ edge_src,
                                                  __half* __restrict__ A, int n) {
    int i = (blockIdx.x * 256 + threadIdx.x) >> 6;  // node = global wave id
    if (i >= n) return;
    int lane = threadIdx.x & 63;
    int g = lane >> 3;    // edge group 0-7
    int c = lane & 7;     // feature lane 0-7, covers halves [12c, 12c+12)
    float di = dis[i];
    float acc[12];
#pragma unroll
    for (int k = 0; k < 12; ++k) acc[k] = 0.f;
    int re0 = row_ptr[i], re1 = row_ptr[i + 1];
    int e0 = re0 + g;
    int s[4]; float m[4];
#pragma unroll
    for (int k = 0; k < 4; ++k) {
        int e = e0 + k * 8;
        int ec = (e < re1) ? e : re0;  // clamp: dummy hits a cached row
        s[k] = edge_src[ec];
        m[k] = (e < re1) ? 1.0f : 0.0f;
    }
    uint2 u[4][3];
#pragma unroll
    for (int k = 0; k < 4; ++k) {
        const uint2* zp = (const uint2*)(Zh + (size_t)s[k] * 96 + c * 12);
        u[k][0] = zp[0]; u[k][1] = zp[1]; u[k][2] = zp[2];
    }
    if (g == 0) {  // self-loop term
        const uint2* zp = (const uint2*)(Zh + (size_t)i * 96 + c * 12);
        acc12(acc, zp[0], zp[1], zp[2], 1.0f);
    }
#pragma unroll
    for (int k = 0; k < 4; ++k) acc12(acc, u[k][0], u[k][1], u[k][2], m[k]);
    for (int e = e0 + 32; e < re1; e += 8) {  // rare heavy nodes
        int s2 = edge_src[e];
        const uint2* zp = (const uint2*)(Zh + (size_t)s2 * 96 + c * 12);
        acc12(acc, zp[0], zp[1], zp[2], 1.0f);
    }
    // Butterfly reduce across the 8 edge groups.
#pragma unroll
    for (int m2 = 8; m2 < 64; m2 <<= 1) {
#pragma unroll
        for (int k = 0; k < 12; ++k) acc[k] += __shfl_xor(acc[k], m2);
    }
    if (g == 0) {
        __half2 h0 = __floats2half2_rn(di * acc[0], di * acc[1]);
        __half2 h1 = __floats2half2_rn(di * acc[2], di * acc[3]);
        __half2 h2 = __floats2half2_rn(di * acc[4], di * acc[5]);
        __half2 h3 = __floats2half2_rn(di * acc[6], di * acc[7]);
        __half2 h4 = __floats2half2_rn(di * acc[8], di * acc[9]);
        __half2 h5 = __floats2half2_rn(di * acc[10], di * acc[11]);
        uint2 o0, o1, o2;
        o0.x = *(unsigned*)&h0; o0.y = *(unsigned*)&h1;
        o1.x = *(unsigned*)&h2; o1.y = *(unsigned*)&h3;
        o2.x = *(unsigned*)&h4; o2.y = *(unsigned*)&h5;
        uint2* ap = (uint2*)(A + (size_t)i * 96 + c * 12);
        ap[0] = o0; ap[1] = o1; ap[2] = o2;
    }
}

// LDS-free MFMA GEMM (96x96, fp16 operands, fp32 accum):
//   Xn[i,f] = leaky( sum_k Agg[i,k]*W[k,f] + b[f] ) (* dis[i] if SCALE)
// A is fp16 row-major [n][96]; Wt is pre-transposed fp16 [f][k] stride 96
// (18 KB -> L2-resident). Fragments loaded straight from global as aligned
// half8: no LDS, no barriers. Fragment layouts (HW-verified, docs §3):
// A[m=lane&15][k=q*8+j], B[k=q*8+j][n=lane&15], D col=lane&15 row=q*4+reg.
template <bool SCALE>
__global__ __launch_bounds__(256) void gemm_mfma(const __half* __restrict__ A,
                                                 const _Float16* __restrict__ Wt,
                                                 const float* __restrict__ b,
                                                 const float* __restrict__ dis,
                                                 __half* __restrict__ Xn, int n) {
    int tid = threadIdx.x;
    int i0 = blockIdx.x * 64;
    int w = tid >> 6, lane = tid & 63;
    int q = lane >> 4, c = lane & 15;
    int arow = i0 + w * 16 + c;
    const _Float16* Ap = (const _Float16*)A;
    half8 af[3];
    if (arow < n) {
#pragma unroll
        for (int kc = 0; kc < 3; ++kc)
            af[kc] = *(const half8*)&Ap[(size_t)arow * 96 + kc * 32 + q * 8];
    } else {
#pragma unroll
        for (int kc = 0; kc < 3; ++kc)
#pragma unroll
            for (int j = 0; j < 8; ++j) af[kc][j] = (_Float16)0.f;
    }
    float dvals[4];
#pragma unroll
    for (int r = 0; r < 4; ++r) {
        int gi = i0 + w * 16 + q * 4 + r;
        dvals[r] = (SCALE && gi < n) ? dis[gi] : 1.f;
    }
#pragma unroll
    for (int nt = 0; nt < 6; ++nt) {
        f32x4 acc = {0.f, 0.f, 0.f, 0.f};
#pragma unroll
        for (int kc = 0; kc < 3; ++kc) {
            half8 bf = *(const half8*)&Wt[(size_t)(nt * 16 + c) * 96 + kc * 32 + q * 8];
            acc = __builtin_amdgcn_mfma_f32_16x16x32_f16(af[kc], bf, acc, 0, 0, 0);
        }
        int col = nt * 16 + c;
        float bias = b[col];
#pragma unroll
        for (int r = 0; r < 4; ++r) {
            int gi = i0 + w * 16 + q * 4 + r;
            if (gi < n) {
                float v = acc[r] + bias;
                v = LEAKY(v);
                if (SCALE) v *= dvals[r];
                ((_Float16*)Xn)[(size_t)gi * 96 + col] = (_Float16)v;
            }
        }
    }
}

// Last-layer GEMM with fused max/mean pooling: never materializes H.
__global__ __launch_bounds__(256) void gemm_pool(const __half* __restrict__ A,
                                                 const _Float16* __restrict__ Wt,
                                                 const float* __restrict__ b,
                                                 const int* __restrict__ batch,
                                                 unsigned* __restrict__ gmaxU,
                                                 float* __restrict__ gsum, int n) {
    __shared__ float pmaxs[4][96];
    __shared__ float psums[4][96];
    int tid = threadIdx.x;
    int i0 = blockIdx.x * 64;
    int w = tid >> 6, lane = tid & 63;
    int q = lane >> 4, c = lane & 15;
    int arow = i0 + w * 16 + c;
    const _Float16* Ap = (const _Float16*)A;
    half8 af[3];
    if (arow < n) {
#pragma unroll
        for (int kc = 0; kc < 3; ++kc)
            af[kc] = *(const half8*)&Ap[(size_t)arow * 96 + kc * 32 + q * 8];
    } else {
#pragma unroll
        for (int kc = 0; kc < 3; ++kc)
#pragma unroll
            for (int j = 0; j < 8; ++j) af[kc][j] = (_Float16)0.f;
    }
    int row0 = i0 + w * 16;
    bool wuni = (row0 + 15 < n) && (batch[row0] == batch[row0 + 15]);
    bool buni = (i0 + 63 < n) && (batch[i0] == batch[i0 + 63]);
    int gw = wuni ? batch[row0] : 0;
#pragma unroll
    for (int nt = 0; nt < 6; ++nt) {
        f32x4 acc = {0.f, 0.f, 0.f, 0.f};
#pragma unroll
        for (int kc = 0; kc < 3; ++kc) {
            half8 bf = *(const half8*)&Wt[(size_t)(nt * 16 + c) * 96 + kc * 32 + q * 8];
            acc = __builtin_amdgcn_mfma_f32_16x16x32_f16(af[kc], bf, acc, 0, 0, 0);
        }
        int col = nt * 16 + c;
        float bias = b[col];
        float v[4];
#pragma unroll
        for (int r = 0; r < 4; ++r) {
            float t = acc[r] + bias;
            v[r] = LEAKY(t);
        }
        if (wuni) {
            float mx = fmaxf(fmaxf(v[0], v[1]), fmaxf(v[2], v[3]));
            float sm = v[0] + v[1] + v[2] + v[3];
            mx = fmaxf(mx, __shfl_xor(mx, 16)); sm += __shfl_xor(sm, 16);
            mx = fmaxf(mx, __shfl_xor(mx, 32)); sm += __shfl_xor(sm, 32);
            if (buni) {
                if (q == 0) { pmaxs[w][col] = mx; psums[w][col] = sm; }
            } else if (q == 0) {
                atomicMax(&gmaxU[gw * 96 + col], encf(mx));
                atomicAdd(&gsum[gw * 96 + col], sm);
            }
        } else {
            int r = 0;
            while (r < 4) {
                int gi = i0 + w * 16 + q * 4 + r;
                if (gi >= n) break;
                int gb = batch[gi];
                float mx = v[r], sm = v[r];
                int r2 = r + 1;
                for (; r2 < 4; ++r2) {
                    int gi2 = i0 + w * 16 + q * 4 + r2;
                    if (gi2 >= n || batch[gi2] != gb) break;
                    mx = fmaxf(mx, v[r2]); sm += v[r2];
                }
                atomicMax(&gmaxU[gb * 96 + col], encf(mx));
                atomicAdd(&gsum[gb * 96 + col], sm);
                r = r2;
            }
        }
    }
    __syncthreads();
    if (buni && tid < 96) {
        float m = fmaxf(fmaxf(pmaxs[0][tid], pmaxs[1][tid]),
                        fmaxf(pmaxs[2][tid], pmaxs[3][tid]));
        float s = psums[0][tid] + psums[1][tid] + psums[2][tid] + psums[3][tid];
        int gb = batch[i0];
        atomicMax(&gmaxU[gb * 96 + tid], encf(m));
        atomicAdd(&gsum[gb * 96 + tid], s);
    }
}

// VALU GEMM for layer 0 (K=16): Xn = leaky(A@W + b) * dis, fp16 out.
__global__ __launch_bounds__(192) void gemm_l0(const float* __restrict__ A,
                                               const float* __restrict__ W,
                                               const float* __restrict__ b,
                                               const float* __restrict__ dis,
                                               __half* __restrict__ Xn, int n) {
    constexpr int KQ = 4;
    __shared__ __align__(16) float4 Al[64 * KQ];
    int tid = threadIdx.x;
    int i0 = blockIdx.x * 64;
    for (int idx = tid; idx < 64 * KQ; idx += 192) {
        int gi = i0 + idx / KQ;
        Al[idx] = (gi < n) ? ((const float4*)A)[(size_t)i0 * KQ + idx]
                           : make_float4(0.f, 0.f, 0.f, 0.f);
    }
    __syncthreads();
    int fq = tid % 24;
    int g = tid / 24;
    const float4* W4 = (const float4*)W;
    float4 bb = ((const float4*)b)[fq];
    float4 acc[8];
#pragma unroll
    for (int r = 0; r < 8; ++r) acc[r] = bb;
    for (int kc = 0; kc < 16; kc += 8) {
        float4 w[8];
#pragma unroll
        for (int kk = 0; kk < 8; ++kk) w[kk] = W4[(size_t)(kc + kk) * 24 + fq];
#pragma unroll
        for (int r = 0; r < 8; ++r) {
            const float4* ar = &Al[(g * 8 + r) * KQ + (kc >> 2)];
#pragma unroll
            for (int k4 = 0; k4 < 2; ++k4) {
                float4 a = ar[k4];
                float4 w0 = w[4 * k4 + 0], w1 = w[4 * k4 + 1];
                float4 w2 = w[4 * k4 + 2], w3 = w[4 * k4 + 3];
                acc[r].x += a.x * w0.x + a.y * w1.x + a.z * w2.x + a.w * w3.x;
                acc[r].y += a.x * w0.y + a.y * w1.y + a.z * w2.y + a.w * w3.y;
                acc[r].z += a.x * w0.z + a.y * w1.z + a.z * w2.z + a.w * w3.z;
                acc[r].w += a.x * w0.w + a.y * w1.w + a.z * w2.w + a.w * w3.w;
            }
        }
    }
#pragma unroll
    for (int r = 0; r < 8; ++r) {
        int gi = i0 + g * 8 + r;
        if (gi < n) {
            float di = dis[gi];
            float4 o;
            o.x = di * LEAKY(acc[r].x); o.y = di * LEAKY(acc[r].y);
            o.z = di * LEAKY(acc[r].z); o.w = di * LEAKY(acc[r].w);
            __half2 h0 = __floats2half2_rn(o.x, o.y);
            __half2 h1 = __floats2half2_rn(o.z, o.w);
            uint2 u;
            u.x = *(unsigned*)&h0;
            u.y = *(unsigned*)&h1;
            ((uint2*)Xn)[(size_t)gi * 24 + fq] = u;
        }
    }
}

__device__ __forceinline__ int lower_bound(const int* b, int n, int v) {
    int lo = 0, hi = n;
    while (lo < hi) {
        int m = (lo + hi) >> 1;
        if (b[m] < v) lo = m + 1; else hi = m;
    }
    return lo;
}

// Pool decode + MLP head: grid = G, block = 96.
__global__ void pool_final(const unsigned* __restrict__ gmaxU,
                           const float* __restrict__ gsum,
                           const int* __restrict__ batch,
                           const float* __restrict__ Wo1, const float* __restrict__ bo1,
                           const float* __restrict__ Wo2, const float* __restrict__ bo2,
                           float* __restrict__ out, int n) {
    __shared__ float pooled[192];
    __shared__ float sh[96];
    int g = blockIdx.x, f = threadIdx.x;
    int s = lower_bound(batch, n, g), e = lower_bound(batch, n, g + 1);
    float cnt = fmaxf((float)(e - s), 1.f);
    pooled[f] = decf(gmaxU[(size_t)g * 96 + f]);
    pooled[96 + f] = gsum[(size_t)g * 96 + f] / cnt;
    __syncthreads();
    float acc = bo1[f];
    for (int k = 0; k < 192; ++k) acc += pooled[k] * Wo1[k * 96 + f];
    float a = LEAKY(acc);
    sh[f] = a * Wo2[f];
    __syncthreads();
    if (f == 0) {
        float sacc = 0.f;
        for (int k = 0; k < 96; ++k) sacc += sh[k];
        out[g] = sacc + bo2[0];
    }
}

extern "C" void kernel_launch(void* const* d_in, const int* in_sizes, int n_in,
                              void* d_out, int out_size, void* d_ws, size_t ws_size,
                              hipStream_t stream) {
    const float* x      = (const float*)d_in[0];
    const int*   eidx   = (const int*)d_in[1];
    const int*   batch  = (const int*)d_in[2];
    const float* W_init = (const float*)d_in[3];
    const float* b_init = (const float*)d_in[4];
    const float* W1 = (const float*)d_in[5];  const float* b1 = (const float*)d_in[6];
    const float* W2 = (const float*)d_in[7];  const float* b2 = (const float*)d_in[8];
    const float* W3 = (const float*)d_in[9];  const float* b3 = (const float*)d_in[10];
    const float* W4 = (const float*)d_in[11]; const float* b4 = (const float*)d_in[12];
    const float* Wo1 = (const float*)d_in[13]; const float* bo1 = (const float*)d_in[14];
    const float* Wo2 = (const float*)d_in[15]; const float* bo2 = (const float*)d_in[16];
    float* out = (float*)d_out;

    const int N = in_sizes[2];
    const int E = in_sizes[1] / 2;
    const int G = out_size;
    const int* src = eidx;
    const int* dst = eidx + E;

    char* ws = (char*)d_ws;
    size_t off = 0;
    auto alloc = [&](size_t bytes) {
        size_t o = off;
        off += (bytes + 255) & ~(size_t)255;
        return o;
    };
    float*    dis      = (float*)(ws + alloc((size_t)N * 4));
    int*      row_ptr  = (int*)(ws + alloc((size_t)(N + 1) * 4));
    int*      cur      = (int*)(ws + alloc((size_t)N * 4));
    int*      deg      = (int*)(ws + alloc((size_t)N * 4));
    int*      bsum     = (int*)(ws + alloc(64 * 4));
    unsigned* gmaxU    = (unsigned*)(ws + alloc((size_t)G * 96 * 4));
    float*    gsumB    = (float*)(ws + alloc((size_t)G * 96 * 4));
    int*      edge_src = (int*)(ws + alloc((size_t)(E + EPAD) * 4));
    float*    Z0       = (float*)(ws + alloc((size_t)N * 16 * 4));
    __half*   ZA       = (__half*)(ws + alloc((size_t)N * 96 * 2));
    __half*   ZB       = (__half*)(ws + alloc((size_t)N * 96 * 2));
    __half*   AggH     = (__half*)(ws + alloc((size_t)N * 96 * 2));
    float*    Agg0     = (float*)(ws + alloc((size_t)N * 16 * 4));
    _Float16* WtG      = (_Float16*)(ws + alloc((size_t)4 * 9216 * 2));
    (void)ws_size; (void)n_in;

    const int nbWave = (N + 3) / 4;       // 4 nodes (waves) per 256-thread block
    const int nbTile = (N + 63) / 64;
    const int nbE    = (E + 255) / 256;
    const int nbScan = (N + SCANB - 1) / SCANB;   // <= 64 (N <= 65536)
    const int nbNode = (N + 255) / 256;

    prep<<<4 + 16, 256, 0, stream>>>(W1, W2, W3, W4, WtG, deg, edge_src + E,
                                     gmaxU, gsumB, N, G);
    // CSR build: hist -> 3-stage scan (fused with dis/Z0/cursors) -> scatter.
    hist_kernel<<<nbE, 256, 0, stream>>>(dst, deg, E);
    scan_a<<<nbScan, 256, 0, stream>>>(deg, row_ptr, bsum, N);
    scan_b<<<1, 64, 0, stream>>>(bsum, nbScan);
    scan_c<<<nbNode, 256, 0, stream>>>(row_ptr, cur, bsum, deg, x, dis, Z0, N, E);
    scatter_kernel<<<nbE, 256, 0, stream>>>(src, dst, cur, edge_src, E);

    // Layer 0: fp32 agg of pre-scaled 16-wide input, then 16x96 VALU GEMM -> fp16 Z1.
    agg_wave0<<<nbWave, 256, 0, stream>>>(Z0, dis, row_ptr, edge_src, Agg0, N);
    gemm_l0<<<nbTile, 192, 0, stream>>>(Agg0, W_init, b_init, dis, ZA, N);

    const float* bs[4] = {b1, b2, b3, b4};
    __half* curZ = ZA;
    __half* nxt = ZB;
    for (int l = 0; l < 4; ++l) {
        agg_wave_h<<<nbWave, 256, 0, stream>>>(curZ, dis, row_ptr, edge_src, AggH, N);
        if (l < 3) {
            gemm_mfma<true><<<nbTile, 256, 0, stream>>>(AggH, WtG + l * 9216, bs[l],
                                                        dis, nxt, N);
            __half* t = curZ; curZ = nxt; nxt = t;
        } else {  // last layer: fused pooling, H never materialized
            gemm_pool<<<nbTile, 256, 0, stream>>>(AggH, WtG + 3 * 9216, bs[3],
                                                  batch, gmaxU, gsumB, N);
        }
    }

    pool_final<<<G, 96, 0, stream>>>(gmaxU, gsumB, batch, Wo1, bo1, Wo2, bo2, out, N);
}

// Round 7
// 321.724 us; speedup vs baseline: 1.1906x; 1.1736x over previous
//
#include <hip/hip_runtime.h>
#include <hip/hip_fp16.h>
#include <math.h>

#define LEAKY(x) ((x) > 0.f ? (x) : 0.01f * (x))
#define BK_SHIFT 9            // 512 nodes per bucket
#define NBMAX 128             // supports N <= 65536
#define BCAP 16384            // edges capacity per bucket (mean 8192 + ~90 sigma)
#define EPAD 64               // zeroed tail of edge_src (legacy; clamp makes it unused)

typedef _Float16 half8 __attribute__((ext_vector_type(8)));
typedef float f32x4 __attribute__((ext_vector_type(4)));

// fp16 -> fp32 multiply-accumulate in ONE VALU op: acc += f16(lo/hi of u) * m.
// Predication folds into m (0.0 or 1.0) -> no divergent edge loop.
#define FMIX_LO(acc, u, m) \
    asm("v_fma_mix_f32 %0, %1, %2, %0 op_sel:[0,0,0] op_sel_hi:[1,0,0]" \
        : "+v"(acc) : "v"(u), "v"(m))
#define FMIX_HI(acc, u, m) \
    asm("v_fma_mix_f32 %0, %1, %2, %0 op_sel:[1,0,0] op_sel_hi:[1,0,0]" \
        : "+v"(acc) : "v"(u), "v"(m))

__device__ __forceinline__ void acc12(float (&acc)[12], uint2 u0, uint2 u1,
                                      uint2 u2, float m) {
    FMIX_LO(acc[0], u0.x, m);  FMIX_HI(acc[1], u0.x, m);
    FMIX_LO(acc[2], u0.y, m);  FMIX_HI(acc[3], u0.y, m);
    FMIX_LO(acc[4], u1.x, m);  FMIX_HI(acc[5], u1.x, m);
    FMIX_LO(acc[6], u1.y, m);  FMIX_HI(acc[7], u1.y, m);
    FMIX_LO(acc[8], u2.x, m);  FMIX_HI(acc[9], u2.x, m);
    FMIX_LO(acc[10], u2.y, m); FMIX_HI(acc[11], u2.y, m);
}

__device__ __forceinline__ void acc4(float (&acc)[4], uint2 u, float m) {
    FMIX_LO(acc[0], u.x, m); FMIX_HI(acc[1], u.x, m);
    FMIX_LO(acc[2], u.y, m); FMIX_HI(acc[3], u.y, m);
}

// Monotone float<->uint encoding for atomicMax on floats (incl. negatives).
__device__ __forceinline__ unsigned encf(float f) {
    unsigned u = __float_as_uint(f);
    return (u & 0x80000000u) ? ~u : (u | 0x80000000u);
}
__device__ __forceinline__ float decf(unsigned u) {
    if (u == 0u) return -INFINITY;  // never-updated cell (empty graph)
    unsigned b = (u & 0x80000000u) ? (u & 0x7fffffffu) : ~u;
    return __uint_as_float(b);
}

// Prep: transpose+convert W1..W4 to fp16 [n][k] (stride 96) once per launch;
// zero bfill, the edge_src pad tail, and the pooling accumulators.
__global__ __launch_bounds__(256) void prep(const float* __restrict__ W1,
                                            const float* __restrict__ W2,
                                            const float* __restrict__ W3,
                                            const float* __restrict__ W4,
                                            _Float16* __restrict__ WtG,
                                            int* __restrict__ bfill,
                                            int* __restrict__ epad,
                                            unsigned* __restrict__ gmaxU,
                                            float* __restrict__ gsum, int G) {
    int bi = blockIdx.x, tid = threadIdx.x;
    if (bi < 4) {
        const float* W = bi == 0 ? W1 : bi == 1 ? W2 : bi == 2 ? W3 : W4;
        _Float16* dst = WtG + bi * 9216;
        for (int idx = tid; idx < 9216; idx += 256) {
            int k = idx / 96, nn = idx % 96;
            dst[nn * 96 + k] = (_Float16)W[idx];
        }
    } else if (bi == 4) {
        for (int i2 = tid; i2 < NBMAX; i2 += 256) bfill[i2] = 0;
        for (int i2 = tid; i2 < EPAD; i2 += 256) epad[i2] = 0;
    } else if (bi == 5) {
        for (int i2 = tid; i2 < G * 96; i2 += 256) gmaxU[i2] = 0u;
    } else {
        for (int i2 = tid; i2 < G * 96; i2 += 256) gsum[i2] = 0.f;
    }
}

// Pass 1 of CSR fill: LDS counting-sort 2048-edge chunks by 512-node bucket,
// reserve per-bucket spans via bfill atomics, flush contiguous runs to tmp
// (fixed-capacity bucket-major: bucket b owns tmp[b*BCAP .. b*BCAP+BCAP)).
// NOTE (round-5 lesson): bucket-staging is mandatory on this chip - a flat
// random 4B scatter produced 52 MB of cross-XCD partial-line HBM writebacks
// at ~920 GB/s (59 us). LDS staging keeps each block's writes line-coherent.
__global__ __launch_bounds__(256) void bin_kernel(const int* __restrict__ src,
                                                  const int* __restrict__ dst,
                                                  int* __restrict__ bfill,
                                                  uint2* __restrict__ tmp,
                                                  int E, int nb) {
    __shared__ int hist[NBMAX];
    __shared__ int scanbuf[NBMAX];
    __shared__ int lofs[NBMAX];
    __shared__ int adj[NBMAX];
    __shared__ uint2 buf[2048];
    __shared__ unsigned char bkt_of[2048];
    int base = blockIdx.x * 2048;
    int cnt = min(2048, E - base);
    int tid = threadIdx.x;
    for (int b = tid; b < NBMAX; b += 256) hist[b] = 0;
    __syncthreads();
    int es[8], ed[8];
#pragma unroll
    for (int k = 0; k < 8; ++k) {
        int l = tid + k * 256;
        if (l < cnt) {
            es[k] = src[base + l];
            ed[k] = dst[base + l];
            atomicAdd(&hist[ed[k] >> BK_SHIFT], 1);
        }
    }
    __syncthreads();
    if (tid < NBMAX) scanbuf[tid] = hist[tid];
    __syncthreads();
    for (int off = 1; off < NBMAX; off <<= 1) {
        int t = (tid < NBMAX && tid >= off) ? scanbuf[tid - off] : 0;
        __syncthreads();
        if (tid < NBMAX) scanbuf[tid] += t;
        __syncthreads();
    }
    if (tid < nb) {
        int cb = hist[tid];
        int start = scanbuf[tid] - cb;   // exclusive (position in buf)
        lofs[tid] = start;
        int g = (cb > 0) ? atomicAdd(&bfill[tid], cb) : 0;
        adj[tid] = tid * BCAP + g - start;  // buf idx -> tmp idx shift
    }
    __syncthreads();
#pragma unroll
    for (int k = 0; k < 8; ++k) {
        int l = tid + k * 256;
        if (l < cnt) {
            int b = ed[k] >> BK_SHIFT;
            int r = atomicAdd(&lofs[b], 1);
            buf[r] = make_uint2((unsigned)es[k], (unsigned)ed[k]);
            bkt_of[r] = (unsigned char)b;
        }
    }
    __syncthreads();
    for (int j = tid; j < cnt; j += 256) {
        int b = bkt_of[j];
        tmp[adj[b] + j] = buf[j];
    }
}

// Pass 2: one block per 512-node bucket. Per-node in-degree (LDS hist), local
// scan -> row_ptr, dis = rsqrt(deg+1), layer-0 pre-scale Z0h = fp16(dis*x),
// and the final edge scatter with LDS cursors (bucket-local span -> writes
// stay line-coherent inside one XCD's L2).
__global__ __launch_bounds__(512) void place2(const uint2* __restrict__ tmp,
                                              const int* __restrict__ bfill,
                                              const float* __restrict__ X,
                                              float* __restrict__ dis,
                                              int* __restrict__ row_ptr,
                                              int* __restrict__ edge_src,
                                              __half* __restrict__ Z0h,
                                              int n, int E, int nb) {
    __shared__ int hist[512];
    __shared__ int sc[512];
    __shared__ int sbf[NBMAX];
    __shared__ int bb_s;
    int b = blockIdx.x;
    int tid = threadIdx.x;
    if (tid < NBMAX) sbf[tid] = (tid < nb) ? bfill[tid] : 0;
    hist[tid] = 0;
    __syncthreads();
    if (tid == 0) {
        int s = 0;
        for (int k = 0; k < b; ++k) s += sbf[k];
        bb_s = s;
    }
    __syncthreads();
    int bb = bb_s;
    int cnt = sbf[b];
    const uint2* mybkt = tmp + (size_t)b * BCAP;
    int node0 = b << BK_SHIFT;
    for (int j = tid; j < cnt; j += 512)
        atomicAdd(&hist[(int)mybkt[j].y - node0], 1);
    __syncthreads();
    int v = hist[tid];
    sc[tid] = v;
    __syncthreads();
    for (int off = 1; off < 512; off <<= 1) {
        int t = (tid >= off) ? sc[tid - off] : 0;
        __syncthreads();
        sc[tid] += t;
        __syncthreads();
    }
    int excl = sc[tid] - v;
    int i = node0 + tid;
    if (i < n) {
        row_ptr[i] = bb + excl;
        float di = rsqrtf((float)(v + 1));  // +1: self-loop
        dis[i] = di;
        const float4* X4 = (const float4*)X;
        uint2* Z2 = (uint2*)Z0h;
#pragma unroll
        for (int j = 0; j < 4; ++j) {
            float4 xv = X4[(size_t)i * 4 + j];
            __half2 h0 = __floats2half2_rn(di * xv.x, di * xv.y);
            __half2 h1 = __floats2half2_rn(di * xv.z, di * xv.w);
            uint2 u;
            u.x = *(unsigned*)&h0;
            u.y = *(unsigned*)&h1;
            Z2[(size_t)i * 4 + j] = u;
        }
    }
    if (b == 0 && tid == 0) row_ptr[n] = E;
    __syncthreads();
    hist[tid] = bb + excl;  // reuse as LDS cursor
    __syncthreads();
    for (int j = tid; j < cnt; j += 512) {
        uint2 ev = mybkt[j];
        int pos = atomicAdd(&hist[(int)ev.y - node0], 1);
        edge_src[pos] = (int)ev.x;
    }
}

// fp16 wave-per-node aggregation, layer 0 (16-wide rows = 32 B fp16).
// 16 edge-groups x 4 uint2-lanes; 2-deep unconditional prefetch with dummy
// indices CLAMPED to re0 (cached row - no phantom fill). fp32 accum via
// v_fma_mix; fp32 out for the K=16 VALU GEMM.
__global__ __launch_bounds__(256) void agg_wave0(const __half* __restrict__ Zh,
                                                 const float* __restrict__ dis,
                                                 const int* __restrict__ row_ptr,
                                                 const int* __restrict__ edge_src,
                                                 float* __restrict__ A, int n) {
    int i = (blockIdx.x * 256 + threadIdx.x) >> 6;  // node = global wave id
    if (i >= n) return;
    int lane = threadIdx.x & 63;
    int g = lane >> 2;   // edge group 0-15
    int c = lane & 3;    // uint2 lane: halves [4c, 4c+4)
    const uint2* Z2 = (const uint2*)Zh;
    float di = dis[i];
    float acc[4];
#pragma unroll
    for (int k = 0; k < 4; ++k) acc[k] = 0.f;
    int re0 = row_ptr[i], re1 = row_ptr[i + 1];
    int e0 = re0 + g;
    int ec0 = (e0 < re1) ? e0 : re0;        // clamp: dummy hits a cached row
    int ec1 = (e0 + 16 < re1) ? e0 + 16 : re0;
    int s0 = edge_src[ec0];
    int s1 = edge_src[ec1];
    float m0 = (e0 < re1) ? 1.f : 0.f;
    float m1 = (e0 + 16 < re1) ? 1.f : 0.f;
    uint2 u0 = Z2[(size_t)s0 * 4 + c];
    uint2 u1 = Z2[(size_t)s1 * 4 + c];
    if (g == 0) acc4(acc, Z2[(size_t)i * 4 + c], 1.0f);  // self-loop
    acc4(acc, u0, m0);
    acc4(acc, u1, m1);
    for (int e = e0 + 32; e < re1; e += 16) {  // rare heavy nodes
        int s = edge_src[e];
        acc4(acc, Z2[(size_t)s * 4 + c], 1.0f);
    }
#pragma unroll
    for (int m = 4; m < 64; m <<= 1) {
#pragma unroll
        for (int k = 0; k < 4; ++k) acc[k] += __shfl_xor(acc[k], m);
    }
    if (g == 0)
        ((float4*)A)[(size_t)i * 4 + c] =
            make_float4(di * acc[0], di * acc[1], di * acc[2], di * acc[3]);
}

// fp16 wave-per-node aggregation, 96-wide (layers 1-4). 8 edge-groups x
// 8 feature-lanes (24 B/lane). 4-deep unconditional batched prefetch:
// 4 edge indices + 12 row loads independent & in flight; deg<=32 branch-free;
// dummy indices clamped to re0 (cached row -> no fill amplification).
// Overflow loop for the ~1e-4 tail. Near its structural floor: per-XCD
// compulsory L2 fill ~8.3 MB x 8 XCDs at ~2.2-2.5 TB/s service ≈ 30 us.
__global__ __launch_bounds__(256) void agg_wave_h(const __half* __restrict__ Zh,
                                                  const float* __restrict__ dis,
                                                  const int* __restrict__ row_ptr,
                                                  const int* __restrict__ edge_src,
                                                  __half* __restrict__ A, int n) {
    int i = (blockIdx.x * 256 + threadIdx.x) >> 6;  // node = global wave id
    if (i >= n) return;
    int lane = threadIdx.x & 63;
    int g = lane >> 3;    // edge group 0-7
    int c = lane & 7;     // feature lane 0-7, covers halves [12c, 12c+12)
    float di = dis[i];
    float acc[12];
#pragma unroll
    for (int k = 0; k < 12; ++k) acc[k] = 0.f;
    int re0 = row_ptr[i], re1 = row_ptr[i + 1];
    int e0 = re0 + g;
    int s[4]; float m[4];
#pragma unroll
    for (int k = 0; k < 4; ++k) {
        int e = e0 + k * 8;
        int ec = (e < re1) ? e : re0;  // clamp: dummy hits a cached row
        s[k] = edge_src[ec];
        m[k] = (e < re1) ? 1.0f : 0.0f;
    }
    uint2 u[4][3];
#pragma unroll
    for (int k = 0; k < 4; ++k) {
        const uint2* zp = (const uint2*)(Zh + (size_t)s[k] * 96 + c * 12);
        u[k][0] = zp[0]; u[k][1] = zp[1]; u[k][2] = zp[2];
    }
    if (g == 0) {  // self-loop term
        const uint2* zp = (const uint2*)(Zh + (size_t)i * 96 + c * 12);
        acc12(acc, zp[0], zp[1], zp[2], 1.0f);
    }
#pragma unroll
    for (int k = 0; k < 4; ++k) acc12(acc, u[k][0], u[k][1], u[k][2], m[k]);
    for (int e = e0 + 32; e < re1; e += 8) {  // rare heavy nodes
        int s2 = edge_src[e];
        const uint2* zp = (const uint2*)(Zh + (size_t)s2 * 96 + c * 12);
        acc12(acc, zp[0], zp[1], zp[2], 1.0f);
    }
    // Butterfly reduce across the 8 edge groups.
#pragma unroll
    for (int m2 = 8; m2 < 64; m2 <<= 1) {
#pragma unroll
        for (int k = 0; k < 12; ++k) acc[k] += __shfl_xor(acc[k], m2);
    }
    if (g == 0) {
        __half2 h0 = __floats2half2_rn(di * acc[0], di * acc[1]);
        __half2 h1 = __floats2half2_rn(di * acc[2], di * acc[3]);
        __half2 h2 = __floats2half2_rn(di * acc[4], di * acc[5]);
        __half2 h3 = __floats2half2_rn(di * acc[6], di * acc[7]);
        __half2 h4 = __floats2half2_rn(di * acc[8], di * acc[9]);
        __half2 h5 = __floats2half2_rn(di * acc[10], di * acc[11]);
        uint2 o0, o1, o2;
        o0.x = *(unsigned*)&h0; o0.y = *(unsigned*)&h1;
        o1.x = *(unsigned*)&h2; o1.y = *(unsigned*)&h3;
        o2.x = *(unsigned*)&h4; o2.y = *(unsigned*)&h5;
        uint2* ap = (uint2*)(A + (size_t)i * 96 + c * 12);
        ap[0] = o0; ap[1] = o1; ap[2] = o2;
    }
}

// LDS-free MFMA GEMM (96x96, fp16 operands, fp32 accum):
//   Xn[i,f] = leaky( sum_k Agg[i,k]*W[k,f] + b[f] ) (* dis[i] if SCALE)
// A is fp16 row-major [n][96]; Wt is pre-transposed fp16 [f][k] stride 96
// (18 KB -> L2-resident). Fragments loaded straight from global as aligned
// half8: no LDS, no barriers. Fragment layouts (HW-verified, docs §3):
// A[m=lane&15][k=q*8+j], B[k=q*8+j][n=lane&15], D col=lane&15 row=q*4+reg.
template <bool SCALE>
__global__ __launch_bounds__(256) void gemm_mfma(const __half* __restrict__ A,
                                                 const _Float16* __restrict__ Wt,
                                                 const float* __restrict__ b,
                                                 const float* __restrict__ dis,
                                                 __half* __restrict__ Xn, int n) {
    int tid = threadIdx.x;
    int i0 = blockIdx.x * 64;
    int w = tid >> 6, lane = tid & 63;
    int q = lane >> 4, c = lane & 15;
    int arow = i0 + w * 16 + c;
    const _Float16* Ap = (const _Float16*)A;
    half8 af[3];
    if (arow < n) {
#pragma unroll
        for (int kc = 0; kc < 3; ++kc)
            af[kc] = *(const half8*)&Ap[(size_t)arow * 96 + kc * 32 + q * 8];
    } else {
#pragma unroll
        for (int kc = 0; kc < 3; ++kc)
#pragma unroll
            for (int j = 0; j < 8; ++j) af[kc][j] = (_Float16)0.f;
    }
    float dvals[4];
#pragma unroll
    for (int r = 0; r < 4; ++r) {
        int gi = i0 + w * 16 + q * 4 + r;
        dvals[r] = (SCALE && gi < n) ? dis[gi] : 1.f;
    }
#pragma unroll
    for (int nt = 0; nt < 6; ++nt) {
        f32x4 acc = {0.f, 0.f, 0.f, 0.f};
#pragma unroll
        for (int kc = 0; kc < 3; ++kc) {
            half8 bf = *(const half8*)&Wt[(size_t)(nt * 16 + c) * 96 + kc * 32 + q * 8];
            acc = __builtin_amdgcn_mfma_f32_16x16x32_f16(af[kc], bf, acc, 0, 0, 0);
        }
        int col = nt * 16 + c;
        float bias = b[col];
#pragma unroll
        for (int r = 0; r < 4; ++r) {
            int gi = i0 + w * 16 + q * 4 + r;
            if (gi < n) {
                float v = acc[r] + bias;
                v = LEAKY(v);
                if (SCALE) v *= dvals[r];
                ((_Float16*)Xn)[(size_t)gi * 96 + col] = (_Float16)v;
            }
        }
    }
}

// Last-layer GEMM with fused max/mean pooling: never materializes H.
__global__ __launch_bounds__(256) void gemm_pool(const __half* __restrict__ A,
                                                 const _Float16* __restrict__ Wt,
                                                 const float* __restrict__ b,
                                                 const int* __restrict__ batch,
                                                 unsigned* __restrict__ gmaxU,
                                                 float* __restrict__ gsum, int n) {
    __shared__ float pmaxs[4][96];
    __shared__ float psums[4][96];
    int tid = threadIdx.x;
    int i0 = blockIdx.x * 64;
    int w = tid >> 6, lane = tid & 63;
    int q = lane >> 4, c = lane & 15;
    int arow = i0 + w * 16 + c;
    const _Float16* Ap = (const _Float16*)A;
    half8 af[3];
    if (arow < n) {
#pragma unroll
        for (int kc = 0; kc < 3; ++kc)
            af[kc] = *(const half8*)&Ap[(size_t)arow * 96 + kc * 32 + q * 8];
    } else {
#pragma unroll
        for (int kc = 0; kc < 3; ++kc)
#pragma unroll
            for (int j = 0; j < 8; ++j) af[kc][j] = (_Float16)0.f;
    }
    int row0 = i0 + w * 16;
    bool wuni = (row0 + 15 < n) && (batch[row0] == batch[row0 + 15]);
    bool buni = (i0 + 63 < n) && (batch[i0] == batch[i0 + 63]);
    int gw = wuni ? batch[row0] : 0;
#pragma unroll
    for (int nt = 0; nt < 6; ++nt) {
        f32x4 acc = {0.f, 0.f, 0.f, 0.f};
#pragma unroll
        for (int kc = 0; kc < 3; ++kc) {
            half8 bf = *(const half8*)&Wt[(size_t)(nt * 16 + c) * 96 + kc * 32 + q * 8];
            acc = __builtin_amdgcn_mfma_f32_16x16x32_f16(af[kc], bf, acc, 0, 0, 0);
        }
        int col = nt * 16 + c;
        float bias = b[col];
        float v[4];
#pragma unroll
        for (int r = 0; r < 4; ++r) {
            float t = acc[r] + bias;
            v[r] = LEAKY(t);
        }
        if (wuni) {
            float mx = fmaxf(fmaxf(v[0], v[1]), fmaxf(v[2], v[3]));
            float sm = v[0] + v[1] + v[2] + v[3];
            mx = fmaxf(mx, __shfl_xor(mx, 16)); sm += __shfl_xor(sm, 16);
            mx = fmaxf(mx, __shfl_xor(mx, 32)); sm += __shfl_xor(sm, 32);
            if (buni) {
                if (q == 0) { pmaxs[w][col] = mx; psums[w][col] = sm; }
            } else if (q == 0) {
                atomicMax(&gmaxU[gw * 96 + col], encf(mx));
                atomicAdd(&gsum[gw * 96 + col], sm);
            }
        } else {
            int r = 0;
            while (r < 4) {
                int gi = i0 + w * 16 + q * 4 + r;
                if (gi >= n) break;
                int gb = batch[gi];
                float mx = v[r], sm = v[r];
                int r2 = r + 1;
                for (; r2 < 4; ++r2) {
                    int gi2 = i0 + w * 16 + q * 4 + r2;
                    if (gi2 >= n || batch[gi2] != gb) break;
                    mx = fmaxf(mx, v[r2]); sm += v[r2];
                }
                atomicMax(&gmaxU[gb * 96 + col], encf(mx));
                atomicAdd(&gsum[gb * 96 + col], sm);
                r = r2;
            }
        }
    }
    __syncthreads();
    if (buni && tid < 96) {
        float m = fmaxf(fmaxf(pmaxs[0][tid], pmaxs[1][tid]),
                        fmaxf(pmaxs[2][tid], pmaxs[3][tid]));
        float s = psums[0][tid] + psums[1][tid] + psums[2][tid] + psums[3][tid];
        int gb = batch[i0];
        atomicMax(&gmaxU[gb * 96 + tid], encf(m));
        atomicAdd(&gsum[gb * 96 + tid], s);
    }
}

// VALU GEMM for layer 0 (K=16): Xn = leaky(A@W + b) * dis, fp16 out.
__global__ __launch_bounds__(192) void gemm_l0(const float* __restrict__ A,
                                               const float* __restrict__ W,
                                               const float* __restrict__ b,
                                               const float* __restrict__ dis,
                                               __half* __restrict__ Xn, int n) {
    constexpr int KQ = 4;
    __shared__ __align__(16) float4 Al[64 * KQ];
    int tid = threadIdx.x;
    int i0 = blockIdx.x * 64;
    for (int idx = tid; idx < 64 * KQ; idx += 192) {
        int gi = i0 + idx / KQ;
        Al[idx] = (gi < n) ? ((const float4*)A)[(size_t)i0 * KQ + idx]
                           : make_float4(0.f, 0.f, 0.f, 0.f);
    }
    __syncthreads();
    int fq = tid % 24;
    int g = tid / 24;
    const float4* W4 = (const float4*)W;
    float4 bb = ((const float4*)b)[fq];
    float4 acc[8];
#pragma unroll
    for (int r = 0; r < 8; ++r) acc[r] = bb;
    for (int kc = 0; kc < 16; kc += 8) {
        float4 w[8];
#pragma unroll
        for (int kk = 0; kk < 8; ++kk) w[kk] = W4[(size_t)(kc + kk) * 24 + fq];
#pragma unroll
        for (int r = 0; r < 8; ++r) {
            const float4* ar = &Al[(g * 8 + r) * KQ + (kc >> 2)];
#pragma unroll
            for (int k4 = 0; k4 < 2; ++k4) {
                float4 a = ar[k4];
                float4 w0 = w[4 * k4 + 0], w1 = w[4 * k4 + 1];
                float4 w2 = w[4 * k4 + 2], w3 = w[4 * k4 + 3];
                acc[r].x += a.x * w0.x + a.y * w1.x + a.z * w2.x + a.w * w3.x;
                acc[r].y += a.x * w0.y + a.y * w1.y + a.z * w2.y + a.w * w3.y;
                acc[r].z += a.x * w0.z + a.y * w1.z + a.z * w2.z + a.w * w3.z;
                acc[r].w += a.x * w0.w + a.y * w1.w + a.z * w2.w + a.w * w3.w;
            }
        }
    }
#pragma unroll
    for (int r = 0; r < 8; ++r) {
        int gi = i0 + g * 8 + r;
        if (gi < n) {
            float di = dis[gi];
            float4 o;
            o.x = di * LEAKY(acc[r].x); o.y = di * LEAKY(acc[r].y);
            o.z = di * LEAKY(acc[r].z); o.w = di * LEAKY(acc[r].w);
            __half2 h0 = __floats2half2_rn(o.x, o.y);
            __half2 h1 = __floats2half2_rn(o.z, o.w);
            uint2 u;
            u.x = *(unsigned*)&h0;
            u.y = *(unsigned*)&h1;
            ((uint2*)Xn)[(size_t)gi * 24 + fq] = u;
        }
    }
}

__device__ __forceinline__ int lower_bound(const int* b, int n, int v) {
    int lo = 0, hi = n;
    while (lo < hi) {
        int m = (lo + hi) >> 1;
        if (b[m] < v) lo = m + 1; else hi = m;
    }
    return lo;
}

// Pool decode + MLP head: grid = G, block = 96.
__global__ void pool_final(const unsigned* __restrict__ gmaxU,
                           const float* __restrict__ gsum,
                           const int* __restrict__ batch,
                           const float* __restrict__ Wo1, const float* __restrict__ bo1,
                           const float* __restrict__ Wo2, const float* __restrict__ bo2,
                           float* __restrict__ out, int n) {
    __shared__ float pooled[192];
    __shared__ float sh[96];
    int g = blockIdx.x, f = threadIdx.x;
    int s = lower_bound(batch, n, g), e = lower_bound(batch, n, g + 1);
    float cnt = fmaxf((float)(e - s), 1.f);
    pooled[f] = decf(gmaxU[(size_t)g * 96 + f]);
    pooled[96 + f] = gsum[(size_t)g * 96 + f] / cnt;
    __syncthreads();
    float acc = bo1[f];
    for (int k = 0; k < 192; ++k) acc += pooled[k] * Wo1[k * 96 + f];
    float a = LEAKY(acc);
    sh[f] = a * Wo2[f];
    __syncthreads();
    if (f == 0) {
        float sacc = 0.f;
        for (int k = 0; k < 96; ++k) sacc += sh[k];
        out[g] = sacc + bo2[0];
    }
}

extern "C" void kernel_launch(void* const* d_in, const int* in_sizes, int n_in,
                              void* d_out, int out_size, void* d_ws, size_t ws_size,
                              hipStream_t stream) {
    const float* x      = (const float*)d_in[0];
    const int*   eidx   = (const int*)d_in[1];
    const int*   batch  = (const int*)d_in[2];
    const float* W_init = (const float*)d_in[3];
    const float* b_init = (const float*)d_in[4];
    const float* W1 = (const float*)d_in[5];  const float* b1 = (const float*)d_in[6];
    const float* W2 = (const float*)d_in[7];  const float* b2 = (const float*)d_in[8];
    const float* W3 = (const float*)d_in[9];  const float* b3 = (const float*)d_in[10];
    const float* W4 = (const float*)d_in[11]; const float* b4 = (const float*)d_in[12];
    const float* Wo1 = (const float*)d_in[13]; const float* bo1 = (const float*)d_in[14];
    const float* Wo2 = (const float*)d_in[15]; const float* bo2 = (const float*)d_in[16];
    float* out = (float*)d_out;

    const int N = in_sizes[2];
    const int E = in_sizes[1] / 2;
    const int G = out_size;
    const int* src = eidx;
    const int* dst = eidx + E;

    const int nbBkt  = (N + (1 << BK_SHIFT) - 1) >> BK_SHIFT;

    char* ws = (char*)d_ws;
    size_t off = 0;
    auto alloc = [&](size_t bytes) {
        size_t o = off;
        off += (bytes + 255) & ~(size_t)255;
        return o;
    };
    float*    dis      = (float*)(ws + alloc((size_t)N * 4));
    int*      row_ptr  = (int*)(ws + alloc((size_t)(N + 1) * 4));
    int*      bfill    = (int*)(ws + alloc(NBMAX * 4));
    unsigned* gmaxU    = (unsigned*)(ws + alloc((size_t)G * 96 * 4));
    float*    gsumB    = (float*)(ws + alloc((size_t)G * 96 * 4));
    int*      edge_src = (int*)(ws + alloc((size_t)(E + EPAD) * 4));
    __half*   Z0h      = (__half*)(ws + alloc((size_t)N * 16 * 2));
    __half*   ZA       = (__half*)(ws + alloc((size_t)N * 96 * 2));
    __half*   ZB       = (__half*)(ws + alloc((size_t)N * 96 * 2));
    __half*   AggH     = (__half*)(ws + alloc((size_t)N * 96 * 2));
    float*    Agg0     = (float*)(ws + alloc((size_t)N * 16 * 4));
    _Float16* WtG      = (_Float16*)(ws + alloc((size_t)4 * 9216 * 2));
    uint2*    tmp      = (uint2*)(ws + alloc((size_t)nbBkt * BCAP * 8));
    (void)ws_size; (void)n_in;

    const int nbWave = (N + 3) / 4;       // 4 nodes (waves) per 256-thread block
    const int nbTile = (N + 63) / 64;

    prep<<<7, 256, 0, stream>>>(W1, W2, W3, W4, WtG, bfill, edge_src + E,
                                gmaxU, gsumB, G);
    bin_kernel<<<(E + 2047) / 2048, 256, 0, stream>>>(src, dst, bfill, tmp, E, nbBkt);
    place2<<<nbBkt, 512, 0, stream>>>(tmp, bfill, x, dis, row_ptr, edge_src, Z0h,
                                      N, E, nbBkt);

    // Layer 0: fp16 agg of pre-scaled 16-wide input, then 16x96 VALU GEMM -> fp16 Z1.
    agg_wave0<<<nbWave, 256, 0, stream>>>(Z0h, dis, row_ptr, edge_src, Agg0, N);
    gemm_l0<<<nbTile, 192, 0, stream>>>(Agg0, W_init, b_init, dis, ZA, N);

    const float* bs[4] = {b1, b2, b3, b4};
    __half* cur = ZA;
    __half* nxt = ZB;
    for (int l = 0; l < 4; ++l) {
        agg_wave_h<<<nbWave, 256, 0, stream>>>(cur, dis, row_ptr, edge_src, AggH, N);
        if (l < 3) {
            gemm_mfma<true><<<nbTile, 256, 0, stream>>>(AggH, WtG + l * 9216, bs[l],
                                                        dis, nxt, N);
            __half* t = cur; cur = nxt; nxt = t;
        } else {  // last layer: fused pooling, H never materialized
            gemm_pool<<<nbTile, 256, 0, stream>>>(AggH, WtG + 3 * 9216, bs[3],
                                                  batch, gmaxU, gsumB, N);
        }
    }

    pool_final<<<G, 96, 0, stream>>>(gmaxU, gsumB, batch, Wo1, bo1, Wo2, bo2, out, N);
}